// Round 1
// baseline (326.590 us; speedup 1.0000x reference)
//
#include <hip/hip_runtime.h>
#include <math.h>

// Problem constants
#define HN 8
#define DK 64
#define LQ 4096
#define LKV 1024
#define DMODEL 512
#define BATCH 2

// ---------------------------------------------------------------------------
// GEMM: C[M x 512] = A[M x 512] * B[512 x 512], fp32, row-major.
// Tile: BM=128, BN=64, BK=16. 256 threads, each computes 8(m) x 4(n).
// A staged TRANSPOSED into LDS (As[k][m]) so inner-loop fragment reads are
// contiguous ds_read_b128.
// ---------------------------------------------------------------------------
__global__ __launch_bounds__(256) void gemm_f32(const float* __restrict__ A,
                                                const float* __restrict__ B,
                                                float* __restrict__ C) {
    __shared__ float As[16][132];  // [k][m], pad 128->132 keeps 16B align, breaks conflicts
    __shared__ float Bs[16][68];   // [k][n], pad 64->68

    const int tid = threadIdx.x;
    const int tx = tid & 15;   // n-group: cols tx*4 .. +3
    const int ty = tid >> 4;   // m-group: rows ty*8 .. +7
    const size_t m0 = (size_t)blockIdx.y * 128;
    const int n0 = blockIdx.x * 64;

    float acc[8][4];
#pragma unroll
    for (int i = 0; i < 8; ++i)
#pragma unroll
        for (int j = 0; j < 4; ++j) acc[i][j] = 0.f;

    for (int k0 = 0; k0 < 512; k0 += 16) {
        // Stage A tile: 128 rows x 16 cols = 512 float4, 2 per thread
#pragma unroll
        for (int i = 0; i < 2; ++i) {
            int idx = tid + i * 256;        // 0..511
            int r = idx >> 2;               // row 0..127
            int c4 = idx & 3;               // float4 within the 16-wide k-slab
            const float4 a = *(const float4*)&A[(m0 + r) * 512 + k0 + c4 * 4];
            As[c4 * 4 + 0][r] = a.x;
            As[c4 * 4 + 1][r] = a.y;
            As[c4 * 4 + 2][r] = a.z;
            As[c4 * 4 + 3][r] = a.w;
        }
        // Stage B tile: 16 rows x 64 cols = 256 float4, 1 per thread
        {
            int r = tid >> 4;               // 0..15
            int c4 = tid & 15;              // 0..15
            *(float4*)&Bs[r][c4 * 4] =
                *(const float4*)&B[(size_t)(k0 + r) * 512 + n0 + c4 * 4];
        }
        __syncthreads();

#pragma unroll
        for (int kk = 0; kk < 16; ++kk) {
            float a[8], b[4];
            *(float4*)&a[0] = *(const float4*)&As[kk][ty * 8];
            *(float4*)&a[4] = *(const float4*)&As[kk][ty * 8 + 4];
            *(float4*)&b[0] = *(const float4*)&Bs[kk][tx * 4];
#pragma unroll
            for (int i = 0; i < 8; ++i)
#pragma unroll
                for (int j = 0; j < 4; ++j)
                    acc[i][j] = fmaf(a[i], b[j], acc[i][j]);
        }
        __syncthreads();
    }

#pragma unroll
    for (int i = 0; i < 8; ++i) {
        *(float4*)&C[(m0 + ty * 8 + i) * 512 + n0 + tx * 4] =
            make_float4(acc[i][0], acc[i][1], acc[i][2], acc[i][3]);
    }
}

// ---------------------------------------------------------------------------
// Sparse sliding-window attention.
// For query c: fd = floor((63-c)/4); candidate KV cols col(r) = r - fd,
// r = 0..15; valid iff r >= fd (row constraint always holds, col < LKV always
// holds for these shapes). Window for a 256-query block: cols
// [max(0, c0/4 - 15), c0/4 + 63] -> <= 80 rows, staged in LDS.
// One thread per query. Q layout: [b][c][h*64+d] (natural q@Wq output).
// ---------------------------------------------------------------------------
__global__ __launch_bounds__(256) void attn_f32(const float* __restrict__ Q,
                                                const float* __restrict__ K,
                                                const float* __restrict__ V,
                                                float* __restrict__ ctx) {
    __shared__ float Ks[80][68];
    __shared__ float Vs[80][68];

    const int tid = threadIdx.x;
    const int c0 = blockIdx.x * 256;
    const int h = blockIdx.y;
    const int b = blockIdx.z;

    const int fd_c0 = (63 - c0) >> 2;        // arithmetic shift = floor div
    const int win_lo = (fd_c0 < 0) ? -fd_c0 : 0;

    // Stage K/V window: 80 rows x 16 float4
    for (int i = tid; i < 80 * 16; i += 256) {
        int row = i >> 4;
        int d4 = i & 15;
        int col = win_lo + row;
        if (col < LKV) {
            size_t base = ((size_t)(b * LKV + col)) * DMODEL + h * DK + d4 * 4;
            *(float4*)&Ks[row][d4 * 4] = *(const float4*)&K[base];
            *(float4*)&Vs[row][d4 * 4] = *(const float4*)&V[base];
        }
    }
    __syncthreads();

    const int c = c0 + tid;
    const int fd = (63 - c) >> 2;

    // Q row into registers
    float4 qv[16];
    const float* qp = &Q[((size_t)(b * LQ + c)) * DMODEL + h * DK];
#pragma unroll
    for (int i = 0; i < 16; ++i) qv[i] = *(const float4*)&qp[i * 4];

    // Scores
    float sc[16];
    float mx = -3.0e38f;
#pragma unroll
    for (int r = 0; r < 16; ++r) {
        int col = r - fd;
        if (col < 0) col = 0;                 // clamped (masked anyway)
        const float* kr = &Ks[col - win_lo][0];
        float s = 0.f;
#pragma unroll
        for (int i = 0; i < 16; ++i) {
            float4 kv = *(const float4*)&kr[i * 4];
            s += qv[i].x * kv.x + qv[i].y * kv.y + qv[i].z * kv.z + qv[i].w * kv.w;
        }
        s *= 0.125f;                          // 1/sqrt(64)
        sc[r] = (r >= fd) ? s : -1.0e30f;
        mx = fmaxf(mx, sc[r]);
    }

    float sum = 0.f;
#pragma unroll
    for (int r = 0; r < 16; ++r) {
        sc[r] = __expf(sc[r] - mx);           // exp(-1e30 - mx) == 0 -> masked
        sum += sc[r];
    }
    const float inv = 1.0f / sum;

    // Weighted V sum
    float acc[64];
#pragma unroll
    for (int i = 0; i < 64; ++i) acc[i] = 0.f;
#pragma unroll
    for (int r = 0; r < 16; ++r) {
        const float w = sc[r] * inv;
        int col = r - fd;
        if (col < 0) col = 0;
        const float* vr = &Vs[col - win_lo][0];
#pragma unroll
        for (int i = 0; i < 64; ++i) acc[i] = fmaf(w, vr[i], acc[i]);
    }

    float* cp = &ctx[((size_t)(b * LQ + c)) * DMODEL + h * DK];
#pragma unroll
    for (int i = 0; i < 16; ++i)
        *(float4*)&cp[i * 4] =
            make_float4(acc[i * 4], acc[i * 4 + 1], acc[i * 4 + 2], acc[i * 4 + 3]);
}

// ---------------------------------------------------------------------------
extern "C" void kernel_launch(void* const* d_in, const int* in_sizes, int n_in,
                              void* d_out, int out_size, void* d_ws, size_t ws_size,
                              hipStream_t stream) {
    const float* q    = (const float*)d_in[0];
    const float* k    = (const float*)d_in[1];
    const float* v    = (const float*)d_in[2];
    const float* Wq   = (const float*)d_in[3];
    const float* Wk   = (const float*)d_in[4];
    const float* Wv   = (const float*)d_in[5];
    const float* Wout = (const float*)d_in[6];
    float* out = (float*)d_out;

    // Workspace layout (fp32): Q[8192x512] K[2048x512] V[2048x512] ctx[8192x512]
    float* Qb = (float*)d_ws;
    float* Kb = Qb + (size_t)BATCH * LQ * DMODEL;
    float* Vb = Kb + (size_t)BATCH * LKV * DMODEL;
    float* Cb = Vb + (size_t)BATCH * LKV * DMODEL;

    dim3 blk(256);

    // Projections
    gemm_f32<<<dim3(512 / 64, (BATCH * LQ) / 128), blk, 0, stream>>>(q, Wq, Qb);
    gemm_f32<<<dim3(512 / 64, (BATCH * LKV) / 128), blk, 0, stream>>>(k, Wk, Kb);
    gemm_f32<<<dim3(512 / 64, (BATCH * LKV) / 128), blk, 0, stream>>>(v, Wv, Vb);

    // Attention
    attn_f32<<<dim3(LQ / 256, HN, BATCH), blk, 0, stream>>>(Qb, Kb, Vb, Cb);

    // Output projection
    gemm_f32<<<dim3(512 / 64, (BATCH * LQ) / 128), blk, 0, stream>>>(Cb, Wout, out);
}

// Round 2
// 138.881 us; speedup vs baseline: 2.3516x; 2.3516x over previous
//
#include <hip/hip_runtime.h>
#include <math.h>

// Problem constants
#define HN 8
#define DK 64
#define LQ 4096
#define LKV 1024
#define DMODEL 512
#define BATCH 2

typedef unsigned short u16;
typedef unsigned int u32;
typedef __attribute__((ext_vector_type(8))) __bf16 bf16x8;
typedef __attribute__((ext_vector_type(4))) float f32x4;
typedef __attribute__((ext_vector_type(8))) u16 u16x8;
typedef __attribute__((ext_vector_type(4))) u16 u16x4;

// fp32 -> bf16 round-to-nearest-even (finite inputs only)
__device__ __forceinline__ u16 f2bf(float f) {
    u32 u = __float_as_uint(f);
    u = u + 0x7fffu + ((u >> 16) & 1u);
    return (u16)(u >> 16);
}

// async 16B global -> LDS (per-lane gptr, wave-uniform LDS base; HW writes base + lane*16)
__device__ __forceinline__ void gl_lds16(const u16* g, u16* l) {
    __builtin_amdgcn_global_load_lds((const __attribute__((address_space(1))) u32*)g,
                                     (__attribute__((address_space(3))) u32*)l, 16, 0, 0);
}

// ---------------------------------------------------------------------------
// bf16 MFMA GEMM body: C[M x 512] = A[M x 512] * W, where Bt = W^T as [n][k].
// Tile 128x128, BK=32, 256 threads = 4 waves in 2x2, each wave 4x4 tiles of
// 16x16x32 MFMA. Staging via global_load_lds width 16. XOR chunk swizzle
// (c ^ ((row>>1)&3)) -> 2-way LDS bank aliasing on frag reads (free).
// ---------------------------------------------------------------------------
__device__ __forceinline__ void gemm_body(const u16* __restrict__ A,
                                          const u16* __restrict__ Bt,
                                          float* __restrict__ C,
                                          int bx, int by) {
    __shared__ u16 As[128 * 32];
    __shared__ u16 Bs[128 * 32];

    const int tid = threadIdx.x;
    const int lane = tid & 63;
    const int wave = tid >> 6;
    const int wm = (wave >> 1) * 64;
    const int wn = (wave & 1) * 64;
    const int quad = lane >> 4;
    const int l16 = lane & 15;
    const size_t m0 = (size_t)by * 128;
    const size_t n0 = (size_t)bx * 128;

    f32x4 acc[4][4] = {};

    for (int k0 = 0; k0 < 512; k0 += 32) {
#pragma unroll
        for (int i = 0; i < 2; ++i) {
            const int id = i * 256 + tid;           // physical chunk 0..511
            const int r = id >> 2;                  // tile row 0..127
            const int cs = id & 3;                  // physical 16B slot in row
            const int c = cs ^ ((r >> 1) & 3);      // logical k-chunk (XOR swizzle)
            const u16* ga = &A[(m0 + r) * 512 + k0 + c * 8];
            const u16* gb = &Bt[(n0 + r) * 512 + k0 + c * 8];
            u16* la = &As[(size_t)(i * 256 + wave * 64) * 8];  // wave-uniform base
            u16* lb = &Bs[(size_t)(i * 256 + wave * 64) * 8];
            gl_lds16(ga, la);
            gl_lds16(gb, lb);
        }
        __syncthreads();  // compiler emits s_waitcnt vmcnt(0) before s_barrier

        bf16x8 af[4], bf[4];
#pragma unroll
        for (int i = 0; i < 4; ++i) {
            const int ra = wm + i * 16 + l16;
            const int ca = quad ^ ((ra >> 1) & 3);
            af[i] = *(const bf16x8*)&As[ra * 32 + ca * 8];
            const int rb = wn + i * 16 + l16;
            const int cb = quad ^ ((rb >> 1) & 3);
            bf[i] = *(const bf16x8*)&Bs[rb * 32 + cb * 8];
        }
#pragma unroll
        for (int i = 0; i < 4; ++i)
#pragma unroll
            for (int j = 0; j < 4; ++j)
                acc[i][j] = __builtin_amdgcn_mfma_f32_16x16x32_bf16(af[i], bf[j], acc[i][j], 0, 0, 0);
        __syncthreads();
    }

    // Epilogue: C/D layout col = lane&15, row = quad*4 + reg
#pragma unroll
    for (int i = 0; i < 4; ++i) {
#pragma unroll
        for (int j = 0; j < 4; ++j) {
            const size_t row = m0 + wm + i * 16 + quad * 4;
            const size_t col = n0 + wn + j * 16 + l16;
#pragma unroll
            for (int t = 0; t < 4; ++t)
                C[(row + t) * 512 + col] = acc[i][j][t];
        }
    }
}

// Fused Q/K/V projections: z selects problem. z=0: M=8192 (grid.y=64); z=1,2: M=2048 (y<16).
__global__ __launch_bounds__(256) void proj_fused(const u16* __restrict__ qb,
                                                  const u16* __restrict__ kb,
                                                  const u16* __restrict__ vb,
                                                  const u16* __restrict__ wqt,
                                                  const u16* __restrict__ wkt,
                                                  const u16* __restrict__ wvt,
                                                  float* __restrict__ Qf,
                                                  float* __restrict__ Kf,
                                                  float* __restrict__ Vf) {
    const int z = blockIdx.z;
    if (z > 0 && blockIdx.y >= 16) return;
    const u16* A = (z == 0) ? qb : (z == 1) ? kb : vb;
    const u16* Bt = (z == 0) ? wqt : (z == 1) ? wkt : wvt;
    float* C = (z == 0) ? Qf : (z == 1) ? Kf : Vf;
    gemm_body(A, Bt, C, blockIdx.x, blockIdx.y);
}

__global__ __launch_bounds__(256) void gemm_out(const u16* __restrict__ A,
                                                const u16* __restrict__ Bt,
                                                float* __restrict__ C) {
    gemm_body(A, Bt, C, blockIdx.x, blockIdx.y);
}

// ---------------------------------------------------------------------------
// fp32 -> bf16 convert, 8 elements/thread
// ---------------------------------------------------------------------------
__global__ __launch_bounds__(256) void cvt_bf16(const float* __restrict__ in,
                                                u16* __restrict__ out, int n8) {
    const int i = blockIdx.x * 256 + threadIdx.x;
    if (i >= n8) return;
    const float4 a = ((const float4*)in)[i * 2];
    const float4 b = ((const float4*)in)[i * 2 + 1];
    u16x8 r;
    r[0] = f2bf(a.x); r[1] = f2bf(a.y); r[2] = f2bf(a.z); r[3] = f2bf(a.w);
    r[4] = f2bf(b.x); r[5] = f2bf(b.y); r[6] = f2bf(b.z); r[7] = f2bf(b.w);
    *(u16x8*)&out[(size_t)i * 8] = r;
}

// Transpose-convert the four 512x512 weights: O[n][k] = bf16(W[k][n]); z selects.
__global__ __launch_bounds__(256) void wtrans(const float* __restrict__ W0,
                                              const float* __restrict__ W1,
                                              const float* __restrict__ W2,
                                              const float* __restrict__ W3,
                                              u16* __restrict__ O0, u16* __restrict__ O1,
                                              u16* __restrict__ O2, u16* __restrict__ O3) {
    const int z = blockIdx.z;
    const float* W = (z == 0) ? W0 : (z == 1) ? W1 : (z == 2) ? W2 : W3;
    u16* O = (z == 0) ? O0 : (z == 1) ? O1 : (z == 2) ? O2 : O3;

    __shared__ float t[32][33];
    const int tx = threadIdx.x;       // 0..31
    const int ty = threadIdx.y;       // 0..7
    const int x = blockIdx.x * 32 + tx;   // source col n
    const int y0 = blockIdx.y * 32;       // source row k base
#pragma unroll
    for (int i = ty; i < 32; i += 8) t[i][tx] = W[(size_t)(y0 + i) * 512 + x];
    __syncthreads();
#pragma unroll
    for (int i = ty; i < 32; i += 8)
        O[(size_t)(blockIdx.x * 32 + i) * 512 + y0 + tx] = f2bf(t[tx][i]);
}

// ---------------------------------------------------------------------------
// Sparse sliding-window attention (fp32 compute, bf16 ctx output).
// For query c: fd = floor((63-c)/4); KV col(r) = r - fd, valid iff r >= fd.
// ---------------------------------------------------------------------------
__global__ __launch_bounds__(256) void attn_f32(const float* __restrict__ Q,
                                                const float* __restrict__ K,
                                                const float* __restrict__ V,
                                                u16* __restrict__ ctx) {
    __shared__ float Ks[80][68];
    __shared__ float Vs[80][68];

    const int tid = threadIdx.x;
    const int c0 = blockIdx.x * 256;
    const int h = blockIdx.y;
    const int b = blockIdx.z;

    const int fd_c0 = (63 - c0) >> 2;
    const int win_lo = (fd_c0 < 0) ? -fd_c0 : 0;

    for (int i = tid; i < 80 * 16; i += 256) {
        int row = i >> 4;
        int d4 = i & 15;
        int col = win_lo + row;
        if (col < LKV) {
            size_t base = ((size_t)(b * LKV + col)) * DMODEL + h * DK + d4 * 4;
            *(float4*)&Ks[row][d4 * 4] = *(const float4*)&K[base];
            *(float4*)&Vs[row][d4 * 4] = *(const float4*)&V[base];
        }
    }
    __syncthreads();

    const int c = c0 + tid;
    const int fd = (63 - c) >> 2;

    float4 qv[16];
    const float* qp = &Q[((size_t)(b * LQ + c)) * DMODEL + h * DK];
#pragma unroll
    for (int i = 0; i < 16; ++i) qv[i] = *(const float4*)&qp[i * 4];

    float sc[16];
    float mx = -3.0e38f;
#pragma unroll
    for (int r = 0; r < 16; ++r) {
        int col = r - fd;
        if (col < 0) col = 0;
        const float* kr = &Ks[col - win_lo][0];
        float s = 0.f;
#pragma unroll
        for (int i = 0; i < 16; ++i) {
            float4 kv = *(const float4*)&kr[i * 4];
            s += qv[i].x * kv.x + qv[i].y * kv.y + qv[i].z * kv.z + qv[i].w * kv.w;
        }
        s *= 0.125f;
        sc[r] = (r >= fd) ? s : -1.0e30f;
        mx = fmaxf(mx, sc[r]);
    }

    float sum = 0.f;
#pragma unroll
    for (int r = 0; r < 16; ++r) {
        sc[r] = __expf(sc[r] - mx);
        sum += sc[r];
    }
    const float inv = 1.0f / sum;

    float acc[64];
#pragma unroll
    for (int i = 0; i < 64; ++i) acc[i] = 0.f;
#pragma unroll
    for (int r = 0; r < 16; ++r) {
        const float w = sc[r] * inv;
        int col = r - fd;
        if (col < 0) col = 0;
        const float* vr = &Vs[col - win_lo][0];
#pragma unroll
        for (int i = 0; i < 64; ++i) acc[i] = fmaf(w, vr[i], acc[i]);
    }

    u16* cp = &ctx[((size_t)(b * LQ + c)) * DMODEL + h * DK];
#pragma unroll
    for (int i = 0; i < 16; ++i) {
        u16x4 o;
        o[0] = f2bf(acc[i * 4 + 0]);
        o[1] = f2bf(acc[i * 4 + 1]);
        o[2] = f2bf(acc[i * 4 + 2]);
        o[3] = f2bf(acc[i * 4 + 3]);
        *(u16x4*)&cp[i * 4] = o;
    }
}

// ---------------------------------------------------------------------------
extern "C" void kernel_launch(void* const* d_in, const int* in_sizes, int n_in,
                              void* d_out, int out_size, void* d_ws, size_t ws_size,
                              hipStream_t stream) {
    const float* q    = (const float*)d_in[0];
    const float* k    = (const float*)d_in[1];
    const float* v    = (const float*)d_in[2];
    const float* Wq   = (const float*)d_in[3];
    const float* Wk   = (const float*)d_in[4];
    const float* Wv   = (const float*)d_in[5];
    const float* Wout = (const float*)d_in[6];
    float* out = (float*)d_out;

    const size_t NQ = (size_t)BATCH * LQ * DMODEL;   // 4,194,304
    const size_t NK = (size_t)BATCH * LKV * DMODEL;  // 1,048,576
    const size_t NW = (size_t)DMODEL * DMODEL;       //   262,144

    // Workspace layout
    float* Qf = (float*)d_ws;          // fp32 Q/K/V projections
    float* Kf = Qf + NQ;
    float* Vf = Kf + NK;
    u16* qb  = (u16*)(Vf + NK);        // bf16 inputs
    u16* kb  = qb + NQ;
    u16* vb  = kb + NK;
    u16* cb  = vb + NK;                // bf16 ctx
    u16* wqt = cb + NQ;                // bf16 transposed weights
    u16* wkt = wqt + NW;
    u16* wvt = wkt + NW;
    u16* wot = wvt + NW;

    // 1) fp32 -> bf16 converts
    cvt_bf16<<<dim3((unsigned)(NQ / 8 / 256)), dim3(256), 0, stream>>>(q, qb, (int)(NQ / 8));
    cvt_bf16<<<dim3((unsigned)(NK / 8 / 256)), dim3(256), 0, stream>>>(k, kb, (int)(NK / 8));
    cvt_bf16<<<dim3((unsigned)(NK / 8 / 256)), dim3(256), 0, stream>>>(v, vb, (int)(NK / 8));

    // 2) weight transpose-convert (all four in one launch)
    wtrans<<<dim3(16, 16, 4), dim3(32, 8), 0, stream>>>(Wq, Wk, Wv, Wout, wqt, wkt, wvt, wot);

    // 3) fused Q/K/V projection GEMMs (bf16 MFMA)
    proj_fused<<<dim3(4, 64, 3), dim3(256), 0, stream>>>(qb, kb, vb, wqt, wkt, wvt, Qf, Kf, Vf);

    // 4) attention (fp32, writes bf16 ctx)
    attn_f32<<<dim3(LQ / 256, HN, BATCH), dim3(256), 0, stream>>>(Qf, Kf, Vf, cb);

    // 5) output projection
    gemm_out<<<dim3(4, 64), dim3(256), 0, stream>>>(cb, wot, out);
}

// Round 3
// 128.349 us; speedup vs baseline: 2.5446x; 1.0821x over previous
//
#include <hip/hip_runtime.h>
#include <math.h>

// Problem constants
#define HN 8
#define DK 64
#define LQ 4096
#define LKV 1024
#define DMODEL 512
#define BATCH 2

typedef unsigned short u16;
typedef unsigned int u32;
typedef __attribute__((ext_vector_type(8))) __bf16 bf16x8;
typedef __attribute__((ext_vector_type(4))) float f32x4;
typedef __attribute__((ext_vector_type(8))) u16 u16x8;

// fp32 -> bf16 round-to-nearest-even (finite inputs only)
__device__ __forceinline__ u16 f2bf(float f) {
    u32 u = __float_as_uint(f);
    u = u + 0x7fffu + ((u >> 16) & 1u);
    return (u16)(u >> 16);
}
__device__ __forceinline__ float bf2f(u16 u) {
    return __uint_as_float(((u32)u) << 16);
}

// async 16B global -> LDS (per-lane gptr, wave-uniform LDS base; HW writes base + lane*16)
__device__ __forceinline__ void gl_lds16(const u16* g, u16* l) {
    __builtin_amdgcn_global_load_lds((const __attribute__((address_space(1))) u32*)g,
                                     (__attribute__((address_space(3))) u32*)l, 16, 0, 0);
}

// ---------------------------------------------------------------------------
// bf16 MFMA GEMM body: C[M x 512] = A[M x 512] * W, Bt = W^T as [n][k].
// Tile 128x128, BK=32, 4 waves 2x2, each wave 4x4 of 16x16x32 MFMA.
// global_load_lds width-16 staging; XOR chunk swizzle -> 2-way aliasing (free).
// BF16OUT: emit bf16 (proj path) else fp32 (final output).
// ---------------------------------------------------------------------------
template <bool BF16OUT>
__device__ __forceinline__ void gemm_body(const u16* __restrict__ A,
                                          const u16* __restrict__ Bt,
                                          void* __restrict__ Cp,
                                          int bx, int by) {
    __shared__ u16 As[128 * 32];
    __shared__ u16 Bs[128 * 32];

    const int tid = threadIdx.x;
    const int lane = tid & 63;
    const int wave = tid >> 6;
    const int wm = (wave >> 1) * 64;
    const int wn = (wave & 1) * 64;
    const int quad = lane >> 4;
    const int l16 = lane & 15;
    const size_t m0 = (size_t)by * 128;
    const size_t n0 = (size_t)bx * 128;

    f32x4 acc[4][4] = {};

    for (int k0 = 0; k0 < 512; k0 += 32) {
#pragma unroll
        for (int i = 0; i < 2; ++i) {
            const int id = i * 256 + tid;
            const int r = id >> 2;
            const int cs = id & 3;
            const int c = cs ^ ((r >> 1) & 3);
            const u16* ga = &A[(m0 + r) * 512 + k0 + c * 8];
            const u16* gb = &Bt[(n0 + r) * 512 + k0 + c * 8];
            u16* la = &As[(size_t)(i * 256 + wave * 64) * 8];
            u16* lb = &Bs[(size_t)(i * 256 + wave * 64) * 8];
            gl_lds16(ga, la);
            gl_lds16(gb, lb);
        }
        __syncthreads();

        bf16x8 af[4], bf[4];
#pragma unroll
        for (int i = 0; i < 4; ++i) {
            const int ra = wm + i * 16 + l16;
            const int ca = quad ^ ((ra >> 1) & 3);
            af[i] = *(const bf16x8*)&As[ra * 32 + ca * 8];
            const int rb = wn + i * 16 + l16;
            const int cb = quad ^ ((rb >> 1) & 3);
            bf[i] = *(const bf16x8*)&Bs[rb * 32 + cb * 8];
        }
#pragma unroll
        for (int i = 0; i < 4; ++i)
#pragma unroll
            for (int j = 0; j < 4; ++j)
                acc[i][j] = __builtin_amdgcn_mfma_f32_16x16x32_bf16(af[i], bf[j], acc[i][j], 0, 0, 0);
        __syncthreads();
    }

    // Epilogue: C/D layout col = lane&15, row = quad*4 + reg
#pragma unroll
    for (int i = 0; i < 4; ++i) {
#pragma unroll
        for (int j = 0; j < 4; ++j) {
            const size_t row = m0 + wm + i * 16 + quad * 4;
            const size_t col = n0 + wn + j * 16 + l16;
#pragma unroll
            for (int t = 0; t < 4; ++t) {
                if (BF16OUT)
                    ((u16*)Cp)[(row + t) * 512 + col] = f2bf(acc[i][j][t]);
                else
                    ((float*)Cp)[(row + t) * 512 + col] = acc[i][j][t];
            }
        }
    }
}

// Fused Q/K/V projections, flat 384-block grid (256 Q + 64 K + 64 V), bf16 out.
__global__ __launch_bounds__(256) void proj_fused(const u16* __restrict__ qb,
                                                  const u16* __restrict__ kb,
                                                  const u16* __restrict__ vb,
                                                  const u16* __restrict__ wqt,
                                                  const u16* __restrict__ wkt,
                                                  const u16* __restrict__ wvt,
                                                  u16* __restrict__ Qb,
                                                  u16* __restrict__ Kb,
                                                  u16* __restrict__ Vb) {
    const int idx = blockIdx.x;
    if (idx < 256)
        gemm_body<true>(qb, wqt, Qb, idx & 3, idx >> 2);
    else if (idx < 320)
        gemm_body<true>(kb, wkt, Kb, (idx - 256) & 3, (idx - 256) >> 2);
    else
        gemm_body<true>(vb, wvt, Vb, (idx - 320) & 3, (idx - 320) >> 2);
}

__global__ __launch_bounds__(256) void gemm_out(const u16* __restrict__ A,
                                                const u16* __restrict__ Bt,
                                                float* __restrict__ C) {
    gemm_body<false>(A, Bt, C, blockIdx.x & 3, blockIdx.x >> 2);
}

// ---------------------------------------------------------------------------
// Fused prep: fp32->bf16 converts for q/k/v + transpose-convert of 4 weights.
// Flat grid: [0,2048) q-cvt, [2048,2560) k-cvt, [2560,3072) v-cvt,
// [3072,4096) weight transpose (4 x 256 tile-blocks of 32x32).
// ---------------------------------------------------------------------------
__global__ __launch_bounds__(256) void prep(const float* __restrict__ q,
                                            const float* __restrict__ k,
                                            const float* __restrict__ v,
                                            const float* __restrict__ Wq,
                                            const float* __restrict__ Wk,
                                            const float* __restrict__ Wv,
                                            const float* __restrict__ Wout,
                                            u16* __restrict__ qb, u16* __restrict__ kb,
                                            u16* __restrict__ vb,
                                            u16* __restrict__ wqt, u16* __restrict__ wkt,
                                            u16* __restrict__ wvt, u16* __restrict__ wot) {
    __shared__ float tbuf[32][33];
    const int bid = blockIdx.x;
    const int tid = threadIdx.x;

    if (bid < 3072) {
        const float* in;
        u16* outp;
        int i;
        if (bid < 2048)      { in = q; outp = qb; i = bid * 256 + tid; }
        else if (bid < 2560) { in = k; outp = kb; i = (bid - 2048) * 256 + tid; }
        else                 { in = v; outp = vb; i = (bid - 2560) * 256 + tid; }
        const float4 a = ((const float4*)in)[i * 2];
        const float4 b = ((const float4*)in)[i * 2 + 1];
        u16x8 r;
        r[0] = f2bf(a.x); r[1] = f2bf(a.y); r[2] = f2bf(a.z); r[3] = f2bf(a.w);
        r[4] = f2bf(b.x); r[5] = f2bf(b.y); r[6] = f2bf(b.z); r[7] = f2bf(b.w);
        *(u16x8*)&outp[(size_t)i * 8] = r;
    } else {
        const int wb = bid - 3072;
        const int z = wb >> 8;        // which weight
        const int t = wb & 255;       // 16x16 grid of 32x32 tiles
        const float* W = (z == 0) ? Wq : (z == 1) ? Wk : (z == 2) ? Wv : Wout;
        u16* O = (z == 0) ? wqt : (z == 1) ? wkt : (z == 2) ? wvt : wot;
        const int tx = tid & 31;
        const int ty = tid >> 5;      // 0..7
        const int x = (t & 15) * 32 + tx;   // source col n
        const int y0 = (t >> 4) * 32;       // source row k base
#pragma unroll
        for (int i = ty; i < 32; i += 8) tbuf[i][tx] = W[(size_t)(y0 + i) * 512 + x];
        __syncthreads();
#pragma unroll
        for (int i = ty; i < 32; i += 8)
            O[(size_t)((t & 15) * 32 + i) * 512 + y0 + tx] = f2bf(tbuf[tx][i]);
    }
}

// ---------------------------------------------------------------------------
// Sparse sliding-window attention, bf16 inputs, fp32 compute, bf16 ctx out.
// For query c: fd = floor((63-c)/4); KV col(r) = r - fd, valid iff r >= fd.
// ---------------------------------------------------------------------------
__global__ __launch_bounds__(256) void attn_f32(const u16* __restrict__ Q,
                                                const u16* __restrict__ K,
                                                const u16* __restrict__ V,
                                                u16* __restrict__ ctx) {
    __shared__ float Ks[80][68];
    __shared__ float Vs[80][68];

    const int tid = threadIdx.x;
    const int c0 = blockIdx.x * 256;
    const int h = blockIdx.y;
    const int b = blockIdx.z;

    const int fd_c0 = (63 - c0) >> 2;
    const int win_lo = (fd_c0 < 0) ? -fd_c0 : 0;

    // Stage K/V window: 80 rows x 8 bf16x8 chunks, convert to fp32 in LDS
    for (int i = tid; i < 80 * 8; i += 256) {
        int row = i >> 3;
        int d8 = i & 7;
        int col = win_lo + row;
        if (col < LKV) {
            size_t base = ((size_t)(b * LKV + col)) * DMODEL + h * DK + d8 * 8;
            u16x8 k8 = *(const u16x8*)&K[base];
            u16x8 v8 = *(const u16x8*)&V[base];
            float4 ka = make_float4(bf2f(k8[0]), bf2f(k8[1]), bf2f(k8[2]), bf2f(k8[3]));
            float4 kb4 = make_float4(bf2f(k8[4]), bf2f(k8[5]), bf2f(k8[6]), bf2f(k8[7]));
            float4 va = make_float4(bf2f(v8[0]), bf2f(v8[1]), bf2f(v8[2]), bf2f(v8[3]));
            float4 vb4 = make_float4(bf2f(v8[4]), bf2f(v8[5]), bf2f(v8[6]), bf2f(v8[7]));
            *(float4*)&Ks[row][d8 * 8] = ka;
            *(float4*)&Ks[row][d8 * 8 + 4] = kb4;
            *(float4*)&Vs[row][d8 * 8] = va;
            *(float4*)&Vs[row][d8 * 8 + 4] = vb4;
        }
    }
    __syncthreads();

    const int c = c0 + tid;
    const int fd = (63 - c) >> 2;

    // Q row (bf16) into fp32 registers
    float qreg[64];
    const u16* qp = &Q[((size_t)(b * LQ + c)) * DMODEL + h * DK];
#pragma unroll
    for (int i = 0; i < 8; ++i) {
        u16x8 t8 = *(const u16x8*)&qp[i * 8];
#pragma unroll
        for (int j = 0; j < 8; ++j) qreg[i * 8 + j] = bf2f(t8[j]);
    }

    float sc[16];
    float mx = -3.0e38f;
#pragma unroll
    for (int r = 0; r < 16; ++r) {
        int col = r - fd;
        if (col < 0) col = 0;
        const float* kr = &Ks[col - win_lo][0];
        float s = 0.f;
#pragma unroll
        for (int i = 0; i < 64; ++i) s = fmaf(qreg[i], kr[i], s);
        s *= 0.125f;
        sc[r] = (r >= fd) ? s : -1.0e30f;
        mx = fmaxf(mx, sc[r]);
    }

    float sum = 0.f;
#pragma unroll
    for (int r = 0; r < 16; ++r) {
        sc[r] = __expf(sc[r] - mx);
        sum += sc[r];
    }
    const float inv = 1.0f / sum;

    float acc[64];
#pragma unroll
    for (int i = 0; i < 64; ++i) acc[i] = 0.f;
#pragma unroll
    for (int r = 0; r < 16; ++r) {
        const float w = sc[r] * inv;
        int col = r - fd;
        if (col < 0) col = 0;
        const float* vr = &Vs[col - win_lo][0];
#pragma unroll
        for (int i = 0; i < 64; ++i) acc[i] = fmaf(w, vr[i], acc[i]);
    }

    u16* cp = &ctx[((size_t)(b * LQ + c)) * DMODEL + h * DK];
#pragma unroll
    for (int i = 0; i < 8; ++i) {
        u16x8 o;
#pragma unroll
        for (int j = 0; j < 8; ++j) o[j] = f2bf(acc[i * 8 + j]);
        *(u16x8*)&cp[i * 8] = o;
    }
}

// ---------------------------------------------------------------------------
extern "C" void kernel_launch(void* const* d_in, const int* in_sizes, int n_in,
                              void* d_out, int out_size, void* d_ws, size_t ws_size,
                              hipStream_t stream) {
    const float* q    = (const float*)d_in[0];
    const float* k    = (const float*)d_in[1];
    const float* v    = (const float*)d_in[2];
    const float* Wq   = (const float*)d_in[3];
    const float* Wk   = (const float*)d_in[4];
    const float* Wv   = (const float*)d_in[5];
    const float* Wout = (const float*)d_in[6];
    float* out = (float*)d_out;

    const size_t NQ = (size_t)BATCH * LQ * DMODEL;   // 4,194,304
    const size_t NK = (size_t)BATCH * LKV * DMODEL;  // 1,048,576
    const size_t NW = (size_t)DMODEL * DMODEL;       //   262,144

    // Workspace layout (all bf16 u16)
    u16* qb  = (u16*)d_ws;      // bf16 inputs
    u16* kb  = qb + NQ;
    u16* vb  = kb + NK;
    u16* Qb  = vb + NK;         // bf16 projections
    u16* Kb  = Qb + NQ;
    u16* Vb  = Kb + NK;
    u16* cb  = Vb + NK;         // bf16 ctx
    u16* wqt = cb + NQ;         // bf16 transposed weights
    u16* wkt = wqt + NW;
    u16* wvt = wkt + NW;
    u16* wot = wvt + NW;

    // 1) fused prep: converts + weight transposes
    prep<<<dim3(4096), dim3(256), 0, stream>>>(q, k, v, Wq, Wk, Wv, Wout,
                                               qb, kb, vb, wqt, wkt, wvt, wot);

    // 2) fused Q/K/V projection GEMMs (bf16 MFMA, bf16 out)
    proj_fused<<<dim3(384), dim3(256), 0, stream>>>(qb, kb, vb, wqt, wkt, wvt, Qb, Kb, Vb);

    // 3) attention (bf16 in, fp32 compute, bf16 ctx)
    attn_f32<<<dim3(LQ / 256, HN, BATCH), dim3(256), 0, stream>>>(Qb, Kb, Vb, cb);

    // 4) output projection (fp32 out)
    gemm_out<<<dim3(256), dim3(256), 0, stream>>>(cb, wot, out);
}